// Round 13
// baseline (129.191 us; speedup 1.0000x reference)
//
#include <hip/hip_runtime.h>
#include <cmath>

// Conductance-based LIF scan: T=512 steps, N=65536 neurons.
// R12: R9's zero-barrier async self-staging, ring deepened 4 -> 6 batches
// (24 slots, 72 KB LDS). Rationale: vmcnt counts LOADS AND STORES; the
// robust wait vmcnt(K_newer_loads) forces retirement of all ops older than
// the K newest loads — including NT stores (which bypass caches and retire
// at HBM-write latency). At depth 4 those stores are only ~2 group-periods
// old -> every wait stalls on store retirement (the invariant ~590 cy/step
// across R7-R11). At depth 6 the stores in the wait window are ~5 periods
// (>10k cy) old -> retired -> waits become load-only.
// Steady-state K = 5 in-flight refill batches x 12 loads = 60 (vmcnt<=63 ok).
//
// Numerics identical to R5/R7/R9 (passed, absmax 0.00390625):
// FMA-contracted, rcp-div, __expf. gA == 0 (ADAPT_INC==0), elided.

__device__ __forceinline__ void gload_lds4(const float* g, float* l) {
    __builtin_amdgcn_global_load_lds(
        (const __attribute__((address_space(1))) unsigned int*)(const void*)g,
        (__attribute__((address_space(3))) unsigned int*)(void*)l,
        4, 0, 0);
}

#define WAITV(n) asm volatile("s_waitcnt vmcnt(" #n ")" ::: "memory")

__global__ __launch_bounds__(256, 1) void lif_scan(
    const float* __restrict__ g_exc,
    const float* __restrict__ g_inh,
    const float* __restrict__ noise,
    const float* __restrict__ v_th,
    const float* __restrict__ tau_ref,
    float* __restrict__ out_spk,   // d_out[0 .. T*N)
    float* __restrict__ out_mem,   // d_out[T*N .. 2*T*N)
    int N, int T,
    float cGE, float cGI, float cALPHA, float cSIGMA)
{
    __shared__ float smem[24][3][256];   // ring: 24 slots = 6 batches, 72 KiB

    const int tid = threadIdx.x;
    const int wq  = (tid >> 6) << 6;            // this wave's LDS quarter base
    const int n   = blockIdx.x * 256 + tid;

    const float vth = v_th[n];
    const float trf = tau_ref[n];

    float v = 0.f, gE = 0.f, gI = 0.f, ref = 0.f, ou = 0.f;

    // stage steps t0..t0+3 into ring slots sb..sb+3 (12 async loads)
    auto issueB = [&](int t0, int sb) {
        #pragma unroll
        for (int k = 0; k < 4; ++k) {
            const size_t row = (size_t)(t0 + k) * (size_t)N + (size_t)n;
            gload_lds4(g_exc + row, &smem[sb + k][0][wq]);
            gload_lds4(g_inh + row, &smem[sb + k][1][wq]);
            gload_lds4(noise + row, &smem[sb + k][2][wq]);
        }
    };

    auto step = [&](float ge_in, float gi_in, float z, int tt) {
        gE = __builtin_fmaf(gE, cGE, ge_in);
        gI = __builtin_fmaf(gI, cGI, gi_in);

        const float gt  = 1.0f + gE + gI;
        const float num = __builtin_fmaf(gI, -0.5f, gE * 3.0f);
        const float vinf = num * __builtin_amdgcn_rcpf(gt);

        const float decay = __expf(-0.05f * gt);

        v = __builtin_fmaf(v - vinf, decay, vinf);

        ou = __builtin_fmaf(ou, cALPHA, cSIGMA * z);
        v = v + ou;

        const bool in_ref = (ref > 0.0f);
        const bool spike  = (v >= vth) && (!in_ref);
        v = (in_ref || spike) ? 0.0f : v;
        ref = spike ? trf : fmaxf(ref - 1.0f, 0.0f);

        const size_t off = (size_t)tt * (size_t)N + (size_t)n;
        __builtin_nontemporal_store(spike ? 1.0f : 0.0f, out_spk + off);
        __builtin_nontemporal_store(v, out_mem + off);
    };

    // one 4-step group: read slots sb..sb+3, refill them for t0+24,
    // compute 4 steps (+8 NT stores)
    auto group = [&](int t0, int sb, bool issue) {
        float vals[12];
        #pragma unroll
        for (int k = 0; k < 4; ++k) {
            vals[k * 3 + 0] = smem[sb + k][0][tid];
            vals[k * 3 + 1] = smem[sb + k][1][tid];
            vals[k * 3 + 2] = smem[sb + k][2][tid];
        }
        // slot data in VGPRs before its refill is issued
        asm volatile("s_waitcnt lgkmcnt(0)" ::: "memory");
        if (issue) issueB(t0 + 24, sb);
        #pragma unroll
        for (int k = 0; k < 4; ++k)
            step(vals[k * 3 + 0], vals[k * 3 + 1], vals[k * 3 + 2], t0 + k);
    };

    // prologue: 6 batches in flight (slots 0,4,8,12,16,20)
    issueB(0,  0);
    issueB(4,  4);
    issueB(8,  8);
    issueB(12, 12);
    issueB(16, 16);
    issueB(20, 20);

    // main: consume batches 0..121 (each refills batch b+6); K = 60 uniform
    for (int p = 0; p < 20; ++p) {
        const int t0 = 24 * p;
        WAITV(60); group(t0,      0,  true);
        WAITV(60); group(t0 + 4,  4,  true);
        WAITV(60); group(t0 + 8,  8,  true);
        WAITV(60); group(t0 + 12, 12, true);
        WAITV(60); group(t0 + 16, 16, true);
        WAITV(60); group(t0 + 20, 20, true);
    }
    WAITV(60); group(480, 0, true);    // refills t=504 (slot 0)
    WAITV(60); group(484, 4, true);    // refills t=508 (slot 4)
    // epilogue: batches 122..127, no refill; K = 60,48,36,24,12,0
    WAITV(60); group(488, 8,  false);
    WAITV(48); group(492, 12, false);
    WAITV(36); group(496, 16, false);
    WAITV(24); group(500, 20, false);
    WAITV(12); group(504, 0,  false);
    WAITV(0);  group(508, 4,  false);
}

extern "C" void kernel_launch(void* const* d_in, const int* in_sizes, int n_in,
                              void* d_out, int out_size, void* d_ws, size_t ws_size,
                              hipStream_t stream) {
    const float* g_exc   = (const float*)d_in[0];
    const float* g_inh   = (const float*)d_in[1];
    const float* noise   = (const float*)d_in[2];
    const float* v_th    = (const float*)d_in[3];
    const float* tau_ref = (const float*)d_in[4];

    const int N = in_sizes[3];            // 65536
    const int T = in_sizes[0] / N;        // 512

    float* out_spk = (float*)d_out;
    float* out_mem = (float*)d_out + (size_t)T * (size_t)N;

    // Constants computed in double exactly as the Python reference does.
    const double ge_decay = exp(-1.0 / 5.0);
    const double gi_decay = exp(-1.0 / 10.0);
    const double ou_alpha = exp(-1.0 / 5.0);
    const double ou_sigma = 0.02 * sqrt(1.0 - ou_alpha * ou_alpha);

    const int block = 256;
    const int grid = (N + block - 1) / block;   // 256 blocks = 1024 waves
    lif_scan<<<grid, block, 0, stream>>>(
        g_exc, g_inh, noise, v_th, tau_ref, out_spk, out_mem,
        N, T,
        (float)ge_decay, (float)gi_decay, (float)ou_alpha, (float)ou_sigma);
}

// Round 14
// 125.803 us; speedup vs baseline: 1.0269x; 1.0269x over previous
//
#include <hip/hip_runtime.h>
#include <cmath>

// Conductance-based LIF scan: T=512 steps, N=65536 neurons.
// R13: STORE-SIDE MERGING on top of R9's zero-barrier async pipeline.
// Steps write v/spike into per-wave LDS staging (ds ops -> lgkmcnt, not
// vmcnt); once per 4-step group each wave transpose-reads 2x ds_read_b128
// and issues 2 NT dwordx4 stores (1KB each) instead of 8 scalar-dword
// stores. Per-CU vmem instrs/step: 20 -> 14; vmcnt waits now contain at
// most 2 stores/group, all >=4 group-periods old (depth-5 ring, K=48).
// Tests the last unfalsified lever: per-vmem-instruction service cost.
//
// Ring: 20 slots = 5 batches (60KB) + obuf 8KB = 68KB LDS.
// Robust wait rule (R9-validated): before consuming batch B wait vmcnt(K),
// K = #loads issued after B's last load = 4 batches x 12 = 48 steady.
//
// Numerics identical to R5/R7/R9/R12 (passed, absmax 0.00390625):
// FMA-contracted, rcp-div, __expf. gA == 0 (ADAPT_INC==0), elided.

typedef float f32x4 __attribute__((ext_vector_type(4)));

__device__ __forceinline__ void gload_lds4(const float* g, float* l) {
    __builtin_amdgcn_global_load_lds(
        (const __attribute__((address_space(1))) unsigned int*)(const void*)g,
        (__attribute__((address_space(3))) unsigned int*)(void*)l,
        4, 0, 0);
}

#define WAITV(n) asm volatile("s_waitcnt vmcnt(" #n ")" ::: "memory")
#define WAITL()  asm volatile("s_waitcnt lgkmcnt(0)" ::: "memory")

__global__ __launch_bounds__(256, 1) void lif_scan(
    const float* __restrict__ g_exc,
    const float* __restrict__ g_inh,
    const float* __restrict__ noise,
    const float* __restrict__ v_th,
    const float* __restrict__ tau_ref,
    float* __restrict__ out_spk,   // d_out[0 .. T*N)
    float* __restrict__ out_mem,   // d_out[T*N .. 2*T*N)
    int N, int T,
    float cGE, float cGI, float cALPHA, float cSIGMA)
{
    __shared__ float smem[20][3][256];   // ring: 20 slots = 5 batches, 60 KiB
    __shared__ float obuf[4][8][64];     // [wave][row: mem k=0-3 | spk 4-7][lane]

    const int tid  = threadIdx.x;
    const int lane = tid & 63;
    const int wid  = tid >> 6;
    const int wq   = wid << 6;                 // wave's neuron base in block
    const int n    = blockIdx.x * 256 + tid;

    const float vth = v_th[n];
    const float trf = tau_ref[n];

    float v = 0.f, gE = 0.f, gI = 0.f, ref = 0.f, ou = 0.f;

    // stage steps t0..t0+3 into ring slots sb..sb+3 (12 async loads)
    auto issueB = [&](int t0, int sb) {
        #pragma unroll
        for (int k = 0; k < 4; ++k) {
            const size_t row = (size_t)(t0 + k) * (size_t)N + (size_t)n;
            gload_lds4(g_exc + row, &smem[sb + k][0][wq]);
            gload_lds4(g_inh + row, &smem[sb + k][1][wq]);
            gload_lds4(noise + row, &smem[sb + k][2][wq]);
        }
    };

    // one neuron step; returns spike flag as float; v updated in place
    auto step = [&](float ge_in, float gi_in, float z) -> float {
        gE = __builtin_fmaf(gE, cGE, ge_in);
        gI = __builtin_fmaf(gI, cGI, gi_in);

        const float gt  = 1.0f + gE + gI;
        const float num = __builtin_fmaf(gI, -0.5f, gE * 3.0f);
        const float vinf = num * __builtin_amdgcn_rcpf(gt);

        const float decay = __expf(-0.05f * gt);

        v = __builtin_fmaf(v - vinf, decay, vinf);

        ou = __builtin_fmaf(ou, cALPHA, cSIGMA * z);
        v = v + ou;

        const bool in_ref = (ref > 0.0f);
        const bool spike  = (v >= vth) && (!in_ref);
        v = (in_ref || spike) ? 0.0f : v;
        ref = spike ? trf : fmaxf(ref - 1.0f, 0.0f);
        return spike ? 1.0f : 0.0f;
    };

    // one 4-step group: ring-read slots sb..sb+3; refill for t0+20;
    // compute 4 steps into obuf; transpose-flush 2x dwordx4 NT stores.
    auto group = [&](int t0, int sb, bool issue) {
        float vals[12];
        #pragma unroll
        for (int k = 0; k < 4; ++k) {
            vals[k * 3 + 0] = smem[sb + k][0][tid];
            vals[k * 3 + 1] = smem[sb + k][1][tid];
            vals[k * 3 + 2] = smem[sb + k][2][tid];
        }
        WAITL();                       // ring data in VGPRs before refill
        if (issue) issueB(t0 + 20, sb);
        #pragma unroll
        for (int k = 0; k < 4; ++k) {
            const float sf = step(vals[k * 3 + 0], vals[k * 3 + 1], vals[k * 3 + 2]);
            obuf[wid][k][lane]     = v;    // post-reset membrane
            obuf[wid][4 + k][lane] = sf;   // spike
        }
        WAITL();                       // ds_writes complete before read-back
        // transpose flush: lane (kr = lane>>4, c = lane&15) handles
        // 4 consecutive neurons of output row t0+kr
        const int kr = lane >> 4;
        const int c  = lane & 15;
        const f32x4 mv = *reinterpret_cast<const f32x4*>(&obuf[wid][kr][c * 4]);
        const f32x4 sv = *reinterpret_cast<const f32x4*>(&obuf[wid][4 + kr][c * 4]);
        const size_t nb = (size_t)blockIdx.x * 256 + (size_t)wq + (size_t)(c * 4);
        const size_t rowoff = (size_t)(t0 + kr) * (size_t)N + nb;
        __builtin_nontemporal_store(mv, (f32x4*)(out_mem + rowoff));
        __builtin_nontemporal_store(sv, (f32x4*)(out_spk + rowoff));
    };

    // prologue: 5 batches in flight (slots 0,4,8,12,16)
    issueB(0,  0);
    issueB(4,  4);
    issueB(8,  8);
    issueB(12, 12);
    issueB(16, 16);

    // groups 0..119: uniform K = 4 in-flight refill batches x 12 = 48
    for (int p = 0; p < 24; ++p) {
        const int t0 = 20 * p;
        WAITV(48); group(t0,      0,  true);
        WAITV(48); group(t0 + 4,  4,  true);
        WAITV(48); group(t0 + 8,  8,  true);
        WAITV(48); group(t0 + 12, 12, true);
        WAITV(48); group(t0 + 16, 16, true);
    }
    // tail: last refills target t=500,504,508
    WAITV(48); group(480, 0,  true);
    WAITV(48); group(484, 4,  true);
    WAITV(48); group(488, 8,  true);
    // epilogue (no refill): newer loads = 48,36,24,12,0
    WAITV(48); group(492, 12, false);
    WAITV(36); group(496, 16, false);
    WAITV(24); group(500, 0,  false);
    WAITV(12); group(504, 4,  false);
    WAITV(0);  group(508, 8,  false);
}

extern "C" void kernel_launch(void* const* d_in, const int* in_sizes, int n_in,
                              void* d_out, int out_size, void* d_ws, size_t ws_size,
                              hipStream_t stream) {
    const float* g_exc   = (const float*)d_in[0];
    const float* g_inh   = (const float*)d_in[1];
    const float* noise   = (const float*)d_in[2];
    const float* v_th    = (const float*)d_in[3];
    const float* tau_ref = (const float*)d_in[4];

    const int N = in_sizes[3];            // 65536
    const int T = in_sizes[0] / N;        // 512

    float* out_spk = (float*)d_out;
    float* out_mem = (float*)d_out + (size_t)T * (size_t)N;

    // Constants computed in double exactly as the Python reference does.
    const double ge_decay = exp(-1.0 / 5.0);
    const double gi_decay = exp(-1.0 / 10.0);
    const double ou_alpha = exp(-1.0 / 5.0);
    const double ou_sigma = 0.02 * sqrt(1.0 - ou_alpha * ou_alpha);

    const int block = 256;
    const int grid = (N + block - 1) / block;   // 256 blocks = 1024 waves
    lif_scan<<<grid, block, 0, stream>>>(
        g_exc, g_inh, noise, v_th, tau_ref, out_spk, out_mem,
        N, T,
        (float)ge_decay, (float)gi_decay, (float)ou_alpha, (float)ou_sigma);
}